// Round 15
// baseline (307.847 us; speedup 1.0000x reference)
//
#include <hip/hip_runtime.h>

#define NEG_SLOPE 0.01f

__device__ __forceinline__ void f4add(float4& a, const float4& v) {
    a.x += v.x; a.y += v.y; a.z += v.z; a.w += v.w;
}

// ---------------------------------------------------------------------------
// cnt[dst[e]] += 1
__global__ __launch_bounds__(256) void k_hist(const int* __restrict__ dst,
                                              int* __restrict__ cnt, int E) {
    int e = blockIdx.x * 256 + threadIdx.x;
    if (e < E) atomicAdd(&cnt[dst[e]], 1);
}

// ---- scan over cnt -> row_ptr; also dinv = rsqrt(1+cnt) -------------------
__global__ __launch_bounds__(256) void k_scan1(const int* __restrict__ cnt,
                                               int* __restrict__ incl,
                                               int* __restrict__ bsum,
                                               float* __restrict__ dinv, int n) {
    __shared__ int sm[256];
    int i = blockIdx.x * 256 + threadIdx.x;
    int t = threadIdx.x;
    int c = (i < n) ? cnt[i] : 0;
    if (i < n) dinv[i] = rsqrtf(1.0f + (float)c);
    sm[t] = c;
    __syncthreads();
    for (int ofs = 1; ofs < 256; ofs <<= 1) {
        int v = (t >= ofs) ? sm[t - ofs] : 0;
        __syncthreads();
        sm[t] += v;
        __syncthreads();
    }
    if (i < n) incl[i] = sm[t];
    if (t == 255) bsum[blockIdx.x] = sm[255];
}

__global__ __launch_bounds__(256) void k_scan2(int* __restrict__ bsum, int nb) {
    __shared__ int sm[256];
    int t = threadIdx.x;
    sm[t] = (t < nb) ? bsum[t] : 0;
    __syncthreads();
    for (int ofs = 1; ofs < 256; ofs <<= 1) {
        int v = (t >= ofs) ? sm[t - ofs] : 0;
        __syncthreads();
        sm[t] += v;
        __syncthreads();
    }
    if (t < nb) bsum[t] = sm[t];
}

__global__ __launch_bounds__(256) void k_scan3(const int* __restrict__ incl,
                                               const int* __restrict__ bsum,
                                               int* __restrict__ row_ptr,
                                               int* __restrict__ fill, int n) {
    int i = blockIdx.x * 256 + threadIdx.x;
    if (i < n) {
        int off = (blockIdx.x > 0) ? bsum[blockIdx.x - 1] : 0;
        row_ptr[i + 1] = incl[i] + off;
        fill[i] = 0;
    }
    if (i == 0) row_ptr[0] = 0;
}

// ---------------------------------------------------------------------------
// Fused layer-1 GEMM + CSR fill. Roles interleaved evenly across blockIdx so
// every CU hosts a mix of latency-bound fill blocks and VALU-bound gemm
// blocks. GEMM K-chunked (32) => LDS 12KB => ~8 blocks/CU.
__global__ __launch_bounds__(256) void k_gemm1_fill(
    const float* __restrict__ x, const float* __restrict__ W,
    const float* __restrict__ dinv, float* __restrict__ y, int n,
    const int* __restrict__ src, const int* __restrict__ dst,
    const int* __restrict__ row_ptr, int* __restrict__ fill,
    int* __restrict__ ssrc, int E, int nbg, int total) {
    __shared__ float ws[32 * 64];   // 8 KB: W chunk (32 k-rows x 64 cols)
    __shared__ float xs[32][32];    // 4 KB: x chunk (32 rows x 32 k)
    const int bid = blockIdx.x;
    const int g  = (int)(((long long)bid * nbg) / total);
    const int g1 = (int)(((long long)(bid + 1) * nbg) / total);
    if (g1 == g) {                  // -------- fill role --------
        const int f = bid - g;
        const int e = f * 256 + (int)threadIdx.x;
        if (e < E) {
            const int d = dst[e];
            const int pos = row_ptr[d] + atomicAdd(&fill[d], 1);
            ssrc[pos] = src[e];
        }
        return;
    }
    // -------- gemm role: rows [g*32, g*32+32) --------
    const int tid = threadIdx.x;
    const int row0 = g * 32;
    const int c = tid & 63;
    const int rbase = (tid >> 6) * 8;
    float acc[8] = {};
    for (int kc = 0; kc < 128; kc += 32) {
        for (int t = tid; t < 512; t += 256)
            ((float4*)ws)[t] = ((const float4*)(W + (size_t)kc * 64))[t];
        {
            const int r = tid >> 3, kk = tid & 7;
            const int row = row0 + r;
            float4 v = (row < n) ? ((const float4*)(x + (size_t)row * 128 + kc))[kk]
                                 : make_float4(0.f, 0.f, 0.f, 0.f);
            ((float4*)&xs[r][0])[kk] = v;
        }
        __syncthreads();
#pragma unroll
        for (int k = 0; k < 32; ++k) {
            const float wv = ws[k * 64 + c];
#pragma unroll
            for (int r = 0; r < 8; ++r) acc[r] += xs[rbase + r][k] * wv;
        }
        __syncthreads();
    }
#pragma unroll
    for (int r = 0; r < 8; ++r) {
        const int row = row0 + rbase + r;
        if (row < n) y[(size_t)row * 64 + c] = dinv[row] * acc[r];
    }
}

// standalone K-chunked GEMM (fallback path): y = dinv * (x @ W)
template <int K>
__global__ __launch_bounds__(256) void k_gemm(const float* __restrict__ x,
                                              const float* __restrict__ W,
                                              const float* __restrict__ dinv,
                                              float* __restrict__ y, int n) {
    __shared__ float ws[32 * 64];
    __shared__ float xs[32][32];
    const int tid = threadIdx.x;
    const int row0 = blockIdx.x * 32;
    const int c = tid & 63;
    const int rbase = (tid >> 6) * 8;
    float acc[8] = {};
    for (int kc = 0; kc < K; kc += 32) {
        for (int t = tid; t < 512; t += 256)
            ((float4*)ws)[t] = ((const float4*)(W + (size_t)kc * 64))[t];
        {
            const int r = tid >> 3, kk = tid & 7;
            const int row = row0 + r;
            float4 v = (row < n) ? ((const float4*)(x + (size_t)row * K + kc))[kk]
                                 : make_float4(0.f, 0.f, 0.f, 0.f);
            ((float4*)&xs[r][0])[kk] = v;
        }
        __syncthreads();
#pragma unroll
        for (int k = 0; k < 32; ++k) {
            const float wv = ws[k * 64 + c];
#pragma unroll
            for (int r = 0; r < 8; ++r) acc[r] += xs[rbase + r][k] * wv;
        }
        __syncthreads();
    }
#pragma unroll
    for (int r = 0; r < 8; ++r) {
        const int row = row0 + rbase + r;
        if (row < n) y[(size_t)row * 64 + c] = dinv[row] * acc[r];
    }
}

// ---------------------------------------------------------------------------
// Gather (standalone): 16 lanes x float4 per node, 16 nodes per block.
template <bool RELU>
__global__ __launch_bounds__(256) void k_gather(const int* __restrict__ row_ptr,
                                                const int* __restrict__ ssrc,
                                                const float* __restrict__ y,
                                                const float* __restrict__ dinv,
                                                const float* __restrict__ b,
                                                float* __restrict__ out, int n) {
    int node = blockIdx.x * 16 + (threadIdx.x >> 4);
    if (node >= n) return;
    int sub = threadIdx.x & 15;
    const float4* Y4 = (const float4*)y;
    float4 a0 = Y4[(size_t)node * 16 + sub];  // self-loop term
    float4 a1 = make_float4(0.f, 0.f, 0.f, 0.f);
    float4 a2 = make_float4(0.f, 0.f, 0.f, 0.f);
    float4 a3 = make_float4(0.f, 0.f, 0.f, 0.f);
    int j = row_ptr[node];
    const int end = row_ptr[node + 1];
    for (; j + 4 <= end; j += 4) {
        int s0 = ssrc[j], s1 = ssrc[j + 1], s2 = ssrc[j + 2], s3 = ssrc[j + 3];
        float4 v0 = Y4[(size_t)s0 * 16 + sub];
        float4 v1 = Y4[(size_t)s1 * 16 + sub];
        float4 v2 = Y4[(size_t)s2 * 16 + sub];
        float4 v3 = Y4[(size_t)s3 * 16 + sub];
        f4add(a0, v0); f4add(a1, v1); f4add(a2, v2); f4add(a3, v3);
    }
    for (; j < end; ++j) {
        int s = ssrc[j];
        float4 v = Y4[(size_t)s * 16 + sub];
        f4add(a1, v);
    }
    f4add(a0, a1); f4add(a2, a3); f4add(a0, a2);
    float di = dinv[node];
    float4 bb = ((const float4*)b)[sub];
    float4 r;
    r.x = di * a0.x + bb.x;
    r.y = di * a0.y + bb.y;
    r.z = di * a0.z + bb.z;
    r.w = di * a0.w + bb.w;
    if (RELU) {
        r.x = (r.x > 0.f) ? r.x : NEG_SLOPE * r.x;
        r.y = (r.y > 0.f) ? r.y : NEG_SLOPE * r.y;
        r.z = (r.z > 0.f) ? r.z : NEG_SLOPE * r.z;
        r.w = (r.w > 0.f) ? r.w : NEG_SLOPE * r.w;
    }
    ((float4*)out)[(size_t)node * 16 + sub] = r;
}

// ---------------------------------------------------------------------------
// Fused layer-1 gather + layer-2 GEMM: block owns 32 nodes. Phase 1 gathers
// h rows (leaky-relu epilogue) into LDS; phase 2 GEMMs them against W2
// (K-chunked) and writes y2 = dinv * (h @ W2). h never touches global.
__global__ __launch_bounds__(256) void k_gather_gemm(
    const int* __restrict__ row_ptr, const int* __restrict__ ssrc,
    const float* __restrict__ y, const float* __restrict__ dinv,
    const float* __restrict__ b1, const float* __restrict__ W2,
    float* __restrict__ y2, int n) {
    __shared__ float hs[32][64];    // 8 KB gathered h rows
    __shared__ float ws[32 * 64];   // 8 KB W2 chunk
    const int tid = threadIdx.x;
    const int row0 = blockIdx.x * 32;
    const int qw = tid >> 4, sub = tid & 15;
    const float4* Y4 = (const float4*)y;
    const float4 bb = ((const float4*)b1)[sub];
#pragma unroll
    for (int half = 0; half < 2; ++half) {
        const int node = row0 + half * 16 + qw;
        if (node < n) {
            float4 a0 = Y4[(size_t)node * 16 + sub];
            float4 a1 = make_float4(0.f, 0.f, 0.f, 0.f);
            float4 a2 = make_float4(0.f, 0.f, 0.f, 0.f);
            float4 a3 = make_float4(0.f, 0.f, 0.f, 0.f);
            int j = row_ptr[node];
            const int end = row_ptr[node + 1];
            for (; j + 4 <= end; j += 4) {
                int s0 = ssrc[j], s1 = ssrc[j + 1], s2 = ssrc[j + 2], s3 = ssrc[j + 3];
                float4 v0 = Y4[(size_t)s0 * 16 + sub];
                float4 v1 = Y4[(size_t)s1 * 16 + sub];
                float4 v2 = Y4[(size_t)s2 * 16 + sub];
                float4 v3 = Y4[(size_t)s3 * 16 + sub];
                f4add(a0, v0); f4add(a1, v1); f4add(a2, v2); f4add(a3, v3);
            }
            for (; j < end; ++j) {
                int s = ssrc[j];
                float4 v = Y4[(size_t)s * 16 + sub];
                f4add(a1, v);
            }
            f4add(a0, a1); f4add(a2, a3); f4add(a0, a2);
            const float di = dinv[node];
            float4 r;
            r.x = di * a0.x + bb.x;
            r.y = di * a0.y + bb.y;
            r.z = di * a0.z + bb.z;
            r.w = di * a0.w + bb.w;
            r.x = (r.x > 0.f) ? r.x : NEG_SLOPE * r.x;
            r.y = (r.y > 0.f) ? r.y : NEG_SLOPE * r.y;
            r.z = (r.z > 0.f) ? r.z : NEG_SLOPE * r.z;
            r.w = (r.w > 0.f) ? r.w : NEG_SLOPE * r.w;
            ((float4*)&hs[half * 16 + qw][0])[sub] = r;
        }
    }
    // phase 2: y2[row] = dinv[row] * (hs[row] @ W2), K=64 in 2 chunks
    const int c = tid & 63;
    const int rbase = (tid >> 6) * 8;
    float acc[8] = {};
    for (int kc = 0; kc < 64; kc += 32) {
        for (int t = tid; t < 512; t += 256)
            ((float4*)ws)[t] = ((const float4*)(W2 + (size_t)kc * 64))[t];
        __syncthreads();   // covers hs writes (first iter) + ws staging
#pragma unroll
        for (int k = 0; k < 32; ++k) {
            const float wv = ws[k * 64 + c];
#pragma unroll
            for (int r = 0; r < 8; ++r) acc[r] += hs[rbase + r][kc + k] * wv;
        }
        __syncthreads();
    }
#pragma unroll
    for (int r = 0; r < 8; ++r) {
        const int row = row0 + rbase + r;
        if (row < n) y2[(size_t)row * 64 + c] = dinv[row] * acc[r];
    }
}

// ---------------------------------------------------------------------------
extern "C" void kernel_launch(void* const* d_in, const int* in_sizes, int n_in,
                              void* d_out, int out_size, void* d_ws, size_t ws_size,
                              hipStream_t stream) {
    const float* x  = (const float*)d_in[0];
    const int*   ei = (const int*)d_in[1];
    const float* W1 = (const float*)d_in[2];
    const float* b1 = (const float*)d_in[3];
    const float* W2 = (const float*)d_in[4];
    const float* b2 = (const float*)d_in[5];
    float* out = (float*)d_out;

    const int N = in_sizes[0] / 128;   // 50000
    const int E = in_sizes[1] / 2;     // 800000
    const int* src = ei;
    const int* dst = ei + E;

    auto align = [](size_t v) { return (v + 255) & ~(size_t)255; };
    char* w = (char*)d_ws;
    size_t o = 0;
    int*   cnt     = (int*)(w + o);  o += align((size_t)N * 4);
    int*   fill    = (int*)(w + o);  o += align((size_t)N * 4);
    int*   incl    = (int*)(w + o);  o += align((size_t)N * 4);
    int*   bsum    = (int*)(w + o);  o += align(256 * 4);
    int*   row_ptr = (int*)(w + o);  o += align((size_t)(N + 1) * 4);
    float* dinv    = (float*)(w + o); o += align((size_t)N * 4);
    int*   ssrc    = (int*)(w + o);  o += align((size_t)E * 4);
    float* y       = (float*)(w + o); o += align((size_t)N * 64 * 4);
    float* y2      = (float*)(w + o); o += align((size_t)N * 64 * 4);
    const bool have_y2 = (o <= ws_size);

    const int nb_n = (N + 255) / 256;
    const int nb_e = (E + 255) / 256;
    const int nb_g = (N + 31) / 32;
    const int nb_a = (N + 15) / 16;

    // ---- preprocessing ----
    hipMemsetAsync(cnt, 0, (size_t)N * 4, stream);
    k_hist <<<nb_e, 256, 0, stream>>>(dst, cnt, E);
    k_scan1<<<nb_n, 256, 0, stream>>>(cnt, incl, bsum, dinv, N);
    k_scan2<<<1,    256, 0, stream>>>(bsum, nb_n);
    k_scan3<<<nb_n, 256, 0, stream>>>(incl, bsum, row_ptr, fill, N);

    // ---- layer 1 GEMM + CSR fill (interleaved roles) ----
    k_gemm1_fill<<<nb_e + nb_g, 256, 0, stream>>>(x, W1, dinv, y, N,
                                                  src, dst, row_ptr, fill, ssrc,
                                                  E, nb_g, nb_e + nb_g);

    if (have_y2) {
        // ---- fused layer-1 gather + layer-2 GEMM, then final gather ----
        k_gather_gemm<<<nb_g, 256, 0, stream>>>(row_ptr, ssrc, y, dinv, b1, W2, y2, N);
        k_gather<false><<<nb_a, 256, 0, stream>>>(row_ptr, ssrc, y2, dinv, b2, out, N);
    } else {
        // ---- fallback: h staged in d_out ----
        k_gather<true><<<nb_a, 256, 0, stream>>>(row_ptr, ssrc, y, dinv, b1, out, N);
        k_gemm<64><<<nb_g, 256, 0, stream>>>(out, W2, dinv, y, N);
        k_gather<false><<<nb_a, 256, 0, stream>>>(row_ptr, ssrc, y, dinv, b2, out, N);
    }
}

// Round 17
// 256.131 us; speedup vs baseline: 1.2019x; 1.2019x over previous
//
#include <hip/hip_runtime.h>

#define NEG_SLOPE 0.01f

__device__ __forceinline__ void f4add(float4& a, const float4& v) {
    a.x += v.x; a.y += v.y; a.z += v.z; a.w += v.w;
}

// ---------------------------------------------------------------------------
// cnt[dst[e]] += 1
__global__ __launch_bounds__(256) void k_hist(const int* __restrict__ dst,
                                              int* __restrict__ cnt, int E) {
    int e = blockIdx.x * 256 + threadIdx.x;
    if (e < E) atomicAdd(&cnt[dst[e]], 1);
}

// ---- scan over cnt -> row_ptr; also dinv = rsqrt(1+cnt) -------------------
__global__ __launch_bounds__(256) void k_scan1(const int* __restrict__ cnt,
                                               int* __restrict__ incl,
                                               int* __restrict__ bsum,
                                               float* __restrict__ dinv, int n) {
    __shared__ int sm[256];
    int i = blockIdx.x * 256 + threadIdx.x;
    int t = threadIdx.x;
    int c = (i < n) ? cnt[i] : 0;
    if (i < n) dinv[i] = rsqrtf(1.0f + (float)c);
    sm[t] = c;
    __syncthreads();
    for (int ofs = 1; ofs < 256; ofs <<= 1) {
        int v = (t >= ofs) ? sm[t - ofs] : 0;
        __syncthreads();
        sm[t] += v;
        __syncthreads();
    }
    if (i < n) incl[i] = sm[t];
    if (t == 255) bsum[blockIdx.x] = sm[255];
}

__global__ __launch_bounds__(256) void k_scan2(int* __restrict__ bsum, int nb) {
    __shared__ int sm[256];
    int t = threadIdx.x;
    sm[t] = (t < nb) ? bsum[t] : 0;
    __syncthreads();
    for (int ofs = 1; ofs < 256; ofs <<= 1) {
        int v = (t >= ofs) ? sm[t - ofs] : 0;
        __syncthreads();
        sm[t] += v;
        __syncthreads();
    }
    if (t < nb) bsum[t] = sm[t];
}

__global__ __launch_bounds__(256) void k_scan3(const int* __restrict__ incl,
                                               const int* __restrict__ bsum,
                                               int* __restrict__ row_ptr,
                                               int* __restrict__ fill, int n) {
    int i = blockIdx.x * 256 + threadIdx.x;
    if (i < n) {
        int off = (blockIdx.x > 0) ? bsum[blockIdx.x - 1] : 0;
        row_ptr[i + 1] = incl[i] + off;
        fill[i] = 0;
    }
    if (i == 0) row_ptr[0] = 0;
}

// ---------------------------------------------------------------------------
// Fused layer-1 GEMM + CSR fill. Roles interleaved evenly across blockIdx so
// every CU hosts a mix of latency-bound fill blocks and VALU-bound gemm
// blocks. GEMM K-chunked (32) => LDS 12KB => ~8 blocks/CU.
// (Round-15 counters: this kernel left the top-5, confirming the K-chunk fix.)
__global__ __launch_bounds__(256) void k_gemm1_fill(
    const float* __restrict__ x, const float* __restrict__ W,
    const float* __restrict__ dinv, float* __restrict__ y, int n,
    const int* __restrict__ src, const int* __restrict__ dst,
    const int* __restrict__ row_ptr, int* __restrict__ fill,
    int* __restrict__ ssrc, int E, int nbg, int total) {
    __shared__ float ws[32 * 64];   // 8 KB: W chunk (32 k-rows x 64 cols)
    __shared__ float xs[32][32];    // 4 KB: x chunk (32 rows x 32 k)
    const int bid = blockIdx.x;
    const int g  = (int)(((long long)bid * nbg) / total);
    const int g1 = (int)(((long long)(bid + 1) * nbg) / total);
    if (g1 == g) {                  // -------- fill role --------
        const int f = bid - g;
        const int e = f * 256 + (int)threadIdx.x;
        if (e < E) {
            const int d = dst[e];
            const int pos = row_ptr[d] + atomicAdd(&fill[d], 1);
            ssrc[pos] = src[e];
        }
        return;
    }
    // -------- gemm role: rows [g*32, g*32+32) --------
    const int tid = threadIdx.x;
    const int row0 = g * 32;
    const int c = tid & 63;
    const int rbase = (tid >> 6) * 8;
    float acc[8] = {};
    for (int kc = 0; kc < 128; kc += 32) {
        for (int t = tid; t < 512; t += 256)
            ((float4*)ws)[t] = ((const float4*)(W + (size_t)kc * 64))[t];
        {
            const int r = tid >> 3, kk = tid & 7;
            const int row = row0 + r;
            float4 v = (row < n) ? ((const float4*)(x + (size_t)row * 128 + kc))[kk]
                                 : make_float4(0.f, 0.f, 0.f, 0.f);
            ((float4*)&xs[r][0])[kk] = v;
        }
        __syncthreads();
#pragma unroll
        for (int k = 0; k < 32; ++k) {
            const float wv = ws[k * 64 + c];
#pragma unroll
            for (int r = 0; r < 8; ++r) acc[r] += xs[rbase + r][k] * wv;
        }
        __syncthreads();
    }
#pragma unroll
    for (int r = 0; r < 8; ++r) {
        const int row = row0 + rbase + r;
        if (row < n) y[(size_t)row * 64 + c] = dinv[row] * acc[r];
    }
}

// standalone K-chunked GEMM: y = dinv * (x @ W)   (12 KB LDS, ~8 blocks/CU)
template <int K>
__global__ __launch_bounds__(256) void k_gemm(const float* __restrict__ x,
                                              const float* __restrict__ W,
                                              const float* __restrict__ dinv,
                                              float* __restrict__ y, int n) {
    __shared__ float ws[32 * 64];
    __shared__ float xs[32][32];
    const int tid = threadIdx.x;
    const int row0 = blockIdx.x * 32;
    const int c = tid & 63;
    const int rbase = (tid >> 6) * 8;
    float acc[8] = {};
    for (int kc = 0; kc < K; kc += 32) {
        for (int t = tid; t < 512; t += 256)
            ((float4*)ws)[t] = ((const float4*)(W + (size_t)kc * 64))[t];
        {
            const int r = tid >> 3, kk = tid & 7;
            const int row = row0 + r;
            float4 v = (row < n) ? ((const float4*)(x + (size_t)row * K + kc))[kk]
                                 : make_float4(0.f, 0.f, 0.f, 0.f);
            ((float4*)&xs[r][0])[kk] = v;
        }
        __syncthreads();
#pragma unroll
        for (int k = 0; k < 32; ++k) {
            const float wv = ws[k * 64 + c];
#pragma unroll
            for (int r = 0; r < 8; ++r) acc[r] += xs[rbase + r][k] * wv;
        }
        __syncthreads();
    }
#pragma unroll
    for (int r = 0; r < 8; ++r) {
        const int row = row0 + rbase + r;
        if (row < n) y[(size_t)row * 64 + c] = dinv[row] * acc[r];
    }
}

// ---------------------------------------------------------------------------
// Gather: 16 lanes x float4 per node, 16 nodes per block. 12 VGPR, high
// occupancy — latency-bound loop NEEDS the TLP (round-15 lesson: fusing this
// into a GEMM kernel ballooned VGPR to 256 and collapsed occupancy to 9.7%).
template <bool RELU>
__global__ __launch_bounds__(256) void k_gather(const int* __restrict__ row_ptr,
                                                const int* __restrict__ ssrc,
                                                const float* __restrict__ y,
                                                const float* __restrict__ dinv,
                                                const float* __restrict__ b,
                                                float* __restrict__ out, int n) {
    int node = blockIdx.x * 16 + (threadIdx.x >> 4);
    if (node >= n) return;
    int sub = threadIdx.x & 15;
    const float4* Y4 = (const float4*)y;
    float4 a0 = Y4[(size_t)node * 16 + sub];  // self-loop term
    float4 a1 = make_float4(0.f, 0.f, 0.f, 0.f);
    float4 a2 = make_float4(0.f, 0.f, 0.f, 0.f);
    float4 a3 = make_float4(0.f, 0.f, 0.f, 0.f);
    int j = row_ptr[node];
    const int end = row_ptr[node + 1];
    for (; j + 4 <= end; j += 4) {
        int s0 = ssrc[j], s1 = ssrc[j + 1], s2 = ssrc[j + 2], s3 = ssrc[j + 3];
        float4 v0 = Y4[(size_t)s0 * 16 + sub];
        float4 v1 = Y4[(size_t)s1 * 16 + sub];
        float4 v2 = Y4[(size_t)s2 * 16 + sub];
        float4 v3 = Y4[(size_t)s3 * 16 + sub];
        f4add(a0, v0); f4add(a1, v1); f4add(a2, v2); f4add(a3, v3);
    }
    for (; j < end; ++j) {
        int s = ssrc[j];
        float4 v = Y4[(size_t)s * 16 + sub];
        f4add(a1, v);
    }
    f4add(a0, a1); f4add(a2, a3); f4add(a0, a2);
    float di = dinv[node];
    float4 bb = ((const float4*)b)[sub];
    float4 r;
    r.x = di * a0.x + bb.x;
    r.y = di * a0.y + bb.y;
    r.z = di * a0.z + bb.z;
    r.w = di * a0.w + bb.w;
    if (RELU) {
        r.x = (r.x > 0.f) ? r.x : NEG_SLOPE * r.x;
        r.y = (r.y > 0.f) ? r.y : NEG_SLOPE * r.y;
        r.z = (r.z > 0.f) ? r.z : NEG_SLOPE * r.z;
        r.w = (r.w > 0.f) ? r.w : NEG_SLOPE * r.w;
    }
    ((float4*)out)[(size_t)node * 16 + sub] = r;
}

// ---------------------------------------------------------------------------
extern "C" void kernel_launch(void* const* d_in, const int* in_sizes, int n_in,
                              void* d_out, int out_size, void* d_ws, size_t ws_size,
                              hipStream_t stream) {
    const float* x  = (const float*)d_in[0];
    const int*   ei = (const int*)d_in[1];
    const float* W1 = (const float*)d_in[2];
    const float* b1 = (const float*)d_in[3];
    const float* W2 = (const float*)d_in[4];
    const float* b2 = (const float*)d_in[5];
    float* out = (float*)d_out;

    const int N = in_sizes[0] / 128;   // 50000
    const int E = in_sizes[1] / 2;     // 800000
    const int* src = ei;
    const int* dst = ei + E;

    auto align = [](size_t v) { return (v + 255) & ~(size_t)255; };
    char* w = (char*)d_ws;
    size_t o = 0;
    int*   cnt     = (int*)(w + o);  o += align((size_t)N * 4);
    int*   fill    = (int*)(w + o);  o += align((size_t)N * 4);
    int*   incl    = (int*)(w + o);  o += align((size_t)N * 4);
    int*   bsum    = (int*)(w + o);  o += align(256 * 4);
    int*   row_ptr = (int*)(w + o);  o += align((size_t)(N + 1) * 4);
    float* dinv    = (float*)(w + o); o += align((size_t)N * 4);
    int*   ssrc    = (int*)(w + o);  o += align((size_t)E * 4);
    float* y       = (float*)(w + o); o += align((size_t)N * 64 * 4);
    float* h       = out;            // d_out doubles as layer-1 activation

    const int nb_n = (N + 255) / 256;
    const int nb_e = (E + 255) / 256;
    const int nb_g = (N + 31) / 32;
    const int nb_a = (N + 15) / 16;

    // ---- preprocessing ----
    hipMemsetAsync(cnt, 0, (size_t)N * 4, stream);
    k_hist <<<nb_e, 256, 0, stream>>>(dst, cnt, E);
    k_scan1<<<nb_n, 256, 0, stream>>>(cnt, incl, bsum, dinv, N);
    k_scan2<<<1,    256, 0, stream>>>(bsum, nb_n);
    k_scan3<<<nb_n, 256, 0, stream>>>(incl, bsum, row_ptr, fill, N);

    // ---- layer 1 GEMM + CSR fill (interleaved roles, K-chunked) ----
    k_gemm1_fill<<<nb_e + nb_g, 256, 0, stream>>>(x, W1, dinv, y, N,
                                                  src, dst, row_ptr, fill, ssrc,
                                                  E, nb_g, nb_e + nb_g);

    // ---- layer 1 aggregate -> h (in d_out), layer 2 GEMM, final aggregate ----
    k_gather<true><<<nb_a, 256, 0, stream>>>(row_ptr, ssrc, y, dinv, b1, h, N);
    k_gemm<64><<<nb_g, 256, 0, stream>>>(h, W2, dinv, y, N);
    k_gather<false><<<nb_a, 256, 0, stream>>>(row_ptr, ssrc, y, dinv, b2, out, N);
}